// Round 5
// baseline (873.115 us; speedup 1.0000x reference)
//
#include <hip/hip_runtime.h>
#include <hip/hip_bf16.h>
#include <cstdint>
#include <cstddef>

#define NN 4096

typedef float f32x4 __attribute__((ext_vector_type(4)));
typedef short s16x8 __attribute__((ext_vector_type(8)));

// ---------- prep: bit-plane mask maskT[chunk][d] (bit i = row sbase+i), deg counts ----------
__global__ __launch_bounds__(256) void k_prep(const float* __restrict__ K,
    unsigned* __restrict__ degc, unsigned long long* __restrict__ maskT) {
  const int lane = threadIdx.x & 63;
  const int wv = threadIdx.x >> 6;
  const int d0 = blockIdx.x * 256 + lane * 4;      // each lane owns 4 columns
  const int sbase = blockIdx.y * 256 + wv * 64;    // this wave's 64-row chunk
  const int chunk = blockIdx.y * 4 + wv;
  unsigned long long w0 = 0, w1 = 0, w2 = 0, w3 = 0;
#pragma unroll 8
  for (int i = 0; i < 64; ++i) {
    const float4 kv = *(const float4*)(K + (size_t)(sbase + i) * NN + d0);
    w0 |= ((unsigned long long)(kv.x != 0.0f)) << i;
    w1 |= ((unsigned long long)(kv.y != 0.0f)) << i;
    w2 |= ((unsigned long long)(kv.z != 0.0f)) << i;
    w3 |= ((unsigned long long)(kv.w != 0.0f)) << i;
  }
  unsigned long long* mp = maskT + (size_t)chunk * NN + d0;
  mp[0] = w0; mp[1] = w1; mp[2] = w2; mp[3] = w3;
  atomicAdd(&degc[d0 + 0], (unsigned)__popcll(w0));
  atomicAdd(&degc[d0 + 1], (unsigned)__popcll(w1));
  atomicAdd(&degc[d0 + 2], (unsigned)__popcll(w2));
  atomicAdd(&degc[d0 + 3], (unsigned)__popcll(w3));
}

// ---------- one-wave register Sinkhorn (lane = row, reg = col at entry) ----------
// 20 alternating LSE normalizations; transposes via LDS (stride-65, conflict-free).
// Ends in layout C (lane = col, reg = row) and leaves log-values in lds[r*65 + col].
__device__ __forceinline__ void lse_norm_reg(float (&m)[64]) {
  float r[32];
#pragma unroll
  for (int j = 0; j < 32; ++j) r[j] = fmaxf(m[j], m[j + 32]);
#pragma unroll
  for (int st = 16; st >= 1; st >>= 1)
#pragma unroll
    for (int j = 0; j < st; ++j) r[j] = fmaxf(r[j], r[j + st]);
  const float mx = r[0];
  float s[32];
#pragma unroll
  for (int j = 0; j < 32; ++j)
    s[j] = __expf(m[j] - mx) + __expf(m[j + 32] - mx);
#pragma unroll
  for (int st = 16; st >= 1; st >>= 1)
#pragma unroll
    for (int j = 0; j < st; ++j) s[j] += s[j + st];
  const float lse = mx + __logf(s[0]);
#pragma unroll
  for (int j = 0; j < 64; ++j) m[j] -= lse;
}

__device__ __forceinline__ void sinkhorn20(float (&m)[64], float* lds, int lane) {
  for (int it = 0; it < 19; ++it) {
    lse_norm_reg(m);
    // transpose (symmetric either direction): write rows, read columns
#pragma unroll
    for (int j = 0; j < 64; ++j) lds[lane * 65 + j] = m[j];
    asm volatile("s_waitcnt lgkmcnt(0)" ::: "memory");   // same-wave DS ordering
#pragma unroll
    for (int j = 0; j < 64; ++j) m[j] = lds[j * 65 + lane];
    asm volatile("" ::: "memory");
  }
  lse_norm_reg(m);                       // it=19, layout C (lane=col, reg=row)
#pragma unroll
  for (int j = 0; j < 64; ++j) lds[j * 65 + lane] = m[j];  // lds[row*65+col] = log val
  asm volatile("s_waitcnt lgkmcnt(0)" ::: "memory");
}

// ---------- layer-0 transform ----------
__global__ __launch_bounds__(256) void k_xform0(const float* __restrict__ K,
    const unsigned* __restrict__ degc,
    const float* __restrict__ cw, const float* __restrict__ cb,
    const float* __restrict__ sw, const float* __restrict__ sb,
    __hip_bfloat16* __restrict__ gHi, __hip_bfloat16* __restrict__ gLo,
    float* __restrict__ xselfT) {
  const int lane = threadIdx.x & 63;
  const int wv = threadIdx.x >> 6;
  const int s = blockIdx.x * 64 + lane;
  const float xv = K[(size_t)s * NN + s];          // diag(K)
  const float ds = rsqrtf((float)degc[s]);
#pragma unroll
  for (int i = 0; i < 16; ++i) {
    const int c = wv * 16 + i;
    const float gv = ds * xv * cw[c];
    const __hip_bfloat16 hi = __float2bfloat16(gv);
    gHi[(size_t)c * NN + s] = hi;
    gLo[(size_t)c * NN + s] = __float2bfloat16(gv - __bfloat162float(hi));
    xselfT[(size_t)c * NN + s] = xv * sw[c] + sb[c] + cb[c];
  }
}

// ---------- fused [sinkhorn(v) by wave0] + layer transform ----------
__global__ __launch_bounds__(256) void k_xformsk(const float* __restrict__ v,
    const float* __restrict__ xoutT, const unsigned* __restrict__ degc,
    const float* __restrict__ cw, const float* __restrict__ cb,
    const float* __restrict__ sw, const float* __restrict__ sb,
    __hip_bfloat16* __restrict__ gHi, __hip_bfloat16* __restrict__ gLo,
    float* __restrict__ xselfT) {
  __shared__ float skl[64 * 65];
  __shared__ float xt[64][64];
  const int tid = threadIdx.x;
  const int lane = tid & 63;
  const int wv = tid >> 6;
  if (wv == 0) {
    float m[64];
#pragma unroll
    for (int j = 0; j < 64; ++j) m[j] = v[lane * 64 + j] * 20.0f;  // /tau
    sinkhorn20(m, skl, lane);
  }
  __syncthreads();
  const int s = blockIdx.x * 64 + lane;
  const float skv = __expf(skl[blockIdx.x * 65 + lane]);  // sk[row=blk][col=lane]
#pragma unroll
  for (int i = 0; i < 16; ++i) {
    const int k = wv * 16 + i;
    xt[k][lane] = xoutT[(size_t)k * NN + s] + skv;  // coalesced
  }
  __syncthreads();
  float accC[16], accS[16];
#pragma unroll
  for (int i = 0; i < 16; ++i) { accC[i] = 0.f; accS[i] = 0.f; }
  for (int k = 0; k < 64; ++k) {
    const float xv = xt[k][lane];
#pragma unroll
    for (int i = 0; i < 16; ++i) {
      const int c = wv * 16 + i;
      accC[i] = fmaf(xv, cw[k * 64 + c], accC[i]);
      accS[i] = fmaf(xv, sw[k * 64 + c], accS[i]);
    }
  }
  const float ds = rsqrtf((float)degc[s]);
#pragma unroll
  for (int i = 0; i < 16; ++i) {
    const int c = wv * 16 + i;
    const float gv = ds * accC[i];
    const __hip_bfloat16 hi = __float2bfloat16(gv);
    gHi[(size_t)c * NN + s] = hi;
    gLo[(size_t)c * NN + s] = __float2bfloat16(gv - __bfloat162float(hi));
    xselfT[(size_t)c * NN + s] = accS[i] + sb[c] + cb[c];
  }
}

// ---------- MFMA masked aggregation + last-block combine (ticket pattern) ----------
__global__ __launch_bounds__(512) void k_aggc(const unsigned long long* __restrict__ maskT,
    const __hip_bfloat16* __restrict__ gHi, const __hip_bfloat16* __restrict__ gLo,
    float* __restrict__ pacc,
    const float* __restrict__ xselfT, const unsigned* __restrict__ degc,
    const float* __restrict__ kw, const float* __restrict__ kb,
    float* __restrict__ xoutT, float* __restrict__ v,
    unsigned* __restrict__ cnt, int nkb, int cpk) {
  const int tid = threadIdx.x;
  const int lane = tid & 63;
  const int wv = tid >> 6;           // 0..7
  const int mtile = wv & 3;          // channel 16-group
  const int nhalf = wv >> 2;         // which 16 d's
  const int l15 = lane & 15;
  const int h = lane >> 4;           // 0..3
  const int d = blockIdx.x * 32 + nhalf * 16 + l15;
  const int ch = mtile * 16 + l15;   // A-operand row (channel)
  const int c0 = blockIdx.y * cpk;
  const short* __restrict__ gh = (const short*)gHi;
  const short* __restrict__ gl = (const short*)gLo;
  f32x4 acch = {0.f, 0.f, 0.f, 0.f};
  f32x4 accl = {0.f, 0.f, 0.f, 0.f};
#pragma unroll 4
  for (int c = c0; c < c0 + cpk; ++c) {
    const unsigned long long w = maskT[(size_t)c * NN + d];
    const unsigned half0 = (unsigned)w, half1 = (unsigned)(w >> 32);
#pragma unroll
    for (int t = 0; t < 2; ++t) {
      const unsigned half = t ? half1 : half0;
      const unsigned hb = (half >> (8 * h)) & 0xFFu;
      s16x8 bfr;
#pragma unroll
      for (int j = 0; j < 8; ++j)
        bfr[j] = (short)(((hb >> j) & 1u) * 0x3F80u);   // bit -> bf16 1.0/0.0
      const size_t abase = (size_t)ch * NN + (size_t)(c * 64 + t * 32 + 8 * h);
      const s16x8 ah = *(const s16x8*)(gh + abase);
      const s16x8 al = *(const s16x8*)(gl + abase);
      acch = __builtin_amdgcn_mfma_f32_16x16x32_bf16(ah, bfr, acch, 0, 0, 0);
      accl = __builtin_amdgcn_mfma_f32_16x16x32_bf16(al, bfr, accl, 0, 0, 0);
    }
  }
  // C/D layout: col = lane&15 (=d), row = (lane>>4)*4 + reg (=channel within mtile)
#pragma unroll
  for (int r = 0; r < 4; ++r) {
    const int chr = mtile * 16 + h * 4 + r;
    pacc[((size_t)blockIdx.y * 64 + chr) * NN + d] = acch[r] + accl[r];
  }
  // ---- ticket: the last y-block for this x combines all partials ----
  __shared__ unsigned ticket;
  __shared__ float red[32][17];
  __threadfence();                   // release pacc stores (all threads)
  __syncthreads();
  if (tid == 0) ticket = atomicAdd(&cnt[blockIdx.x], 1u);
  __syncthreads();
  if (ticket != (unsigned)(nkb - 1)) return;
  __threadfence();                   // acquire other blocks' pacc
  const int dc = blockIdx.x * 32 + (tid & 31);
  const int cg = tid >> 5;           // 0..15 -> 4 channels each
  const float dd = rsqrtf((float)degc[dc]);
  float p = 0.f;
#pragma unroll
  for (int i = 0; i < 4; ++i) {
    const int c = cg * 4 + i;
    float a = 0.f;
    for (int k2 = 0; k2 < nkb; ++k2) a += pacc[((size_t)k2 * 64 + c) * NN + dc];
    const float xo = xselfT[(size_t)c * NN + dc] + dd * a;
    xoutT[(size_t)c * NN + dc] = xo;
    p = fmaf(xo, kw[c], p);
  }
  red[tid & 31][cg] = p;
  __syncthreads();
  if (tid < 32) {
    float sum = kb[0];
#pragma unroll
    for (int q = 0; q < 16; ++q) sum += red[tid][q];
    v[blockIdx.x * 32 + tid] = sum;
    if (tid == 0) cnt[blockIdx.x] = 0;   // self-reset for next layer / replay
  }
}

// ---------- fused [sinkhorn(v2) by wave0] + final scores -> pre-transposed sT ----------
__global__ __launch_bounds__(256) void k_scoresk(const float* __restrict__ v,
    const float* __restrict__ xoutT, const float* __restrict__ fw,
    const float* __restrict__ fb, float* __restrict__ sT) {
  __shared__ float skl[64 * 65];
  const int tid = threadIdx.x;
  const int lane = tid & 63;
  const int wv = tid >> 6;
  if (wv == 0) {
    float m[64];
#pragma unroll
    for (int j = 0; j < 64; ++j) m[j] = v[lane * 64 + j] * 20.0f;
    sinkhorn20(m, skl, lane);
  }
  __syncthreads();
  const int n = blockIdx.x * 256 + tid;
  const float skv = __expf(skl[(n >> 6) * 65 + (n & 63)]);
  float acc = 0.f, sumw = 0.f;
#pragma unroll 8
  for (int k = 0; k < 64; ++k) {
    const float w = fw[k];
    sumw += w;
    acc = fmaf(xoutT[(size_t)k * NN + n], w, acc);
  }
  sT[(n & 63) * 64 + (n >> 6)] = (acc + skv * sumw + fb[0]) * 20.0f;
}

// ---------- final Sinkhorn: one wave, sT -> out ----------
__global__ __launch_bounds__(64) void k_skfinal(const float* __restrict__ sT,
                                                float* __restrict__ out) {
  __shared__ float lds[64 * 65];
  const int lane = threadIdx.x;
  float m[64];
#pragma unroll
  for (int j = 0; j < 64; ++j) m[j] = sT[lane * 64 + j];
  sinkhorn20(m, lds, lane);
  // layout C: m[r] = log val at [r][lane]; coalesced store
#pragma unroll
  for (int r = 0; r < 64; ++r) out[r * 64 + lane] = __expf(m[r]);
}

extern "C" void kernel_launch(void* const* d_in, const int* in_sizes, int n_in,
                              void* d_out, int out_size, void* d_ws, size_t ws_size,
                              hipStream_t stream) {
  const float* K = (const float*)d_in[0];
  const float* cw[3] = {(const float*)d_in[4],  (const float*)d_in[10], (const float*)d_in[16]};
  const float* cb[3] = {(const float*)d_in[5],  (const float*)d_in[11], (const float*)d_in[17]};
  const float* sw[3] = {(const float*)d_in[6],  (const float*)d_in[12], (const float*)d_in[18]};
  const float* sb[3] = {(const float*)d_in[7],  (const float*)d_in[13], (const float*)d_in[19]};
  const float* kw[3] = {(const float*)d_in[8],  (const float*)d_in[14], (const float*)d_in[20]};
  const float* kb[3] = {(const float*)d_in[9],  (const float*)d_in[15], (const float*)d_in[21]};
  const float* fw = (const float*)d_in[22];
  const float* fb = (const float*)d_in[23];
  float* out = (float*)d_out;

  char* ws = (char*)d_ws;
  const size_t KB = 1024, MB = 1024 * 1024;
  unsigned* degc            = (unsigned*)(ws + 0);                // 16 KB
  unsigned* cnt             = (unsigned*)(ws + 16 * KB);          // 512 B
  float* v                  = (float*)(ws + 32 * KB);             // 16 KB
  float* sT                 = (float*)(ws + 48 * KB);             // 16 KB
  unsigned long long* maskT = (unsigned long long*)(ws + 64 * KB);// 2 MB
  __hip_bfloat16* gHi       = (__hip_bfloat16*)(ws + 64 * KB + 2 * MB);            // 512 KB
  __hip_bfloat16* gLo       = (__hip_bfloat16*)(ws + 64 * KB + 2 * MB + 512 * KB); // 512 KB
  float* xselfT             = (float*)(ws + 64 * KB + 3 * MB);    // 1 MB
  float* xoutT              = (float*)(ws + 64 * KB + 4 * MB);    // 1 MB
  float* pacc               = (float*)(ws + 64 * KB + 5 * MB);    // NKB MB
  (void)in_sizes; (void)n_in; (void)out_size;

  int NKB = 8;
  while (NKB > 1 && 64 * KB + (5 + (size_t)NKB) * MB > ws_size) NKB >>= 1;
  const int cpk = 64 / NKB;

  hipMemsetAsync(ws, 0, 17 * KB, stream);          // degc + cnt
  k_prep<<<dim3(16, 16), 256, 0, stream>>>(K, degc, maskT);

  k_xform0<<<64, 256, 0, stream>>>(K, degc, cw[0], cb[0], sw[0], sb[0], gHi, gLo, xselfT);
  k_aggc<<<dim3(128, NKB), 512, 0, stream>>>(maskT, gHi, gLo, pacc, xselfT, degc,
                                             kw[0], kb[0], xoutT, v, cnt, NKB, cpk);
  for (int l = 1; l < 3; ++l) {
    k_xformsk<<<64, 256, 0, stream>>>(v, xoutT, degc, cw[l], cb[l], sw[l], sb[l],
                                      gHi, gLo, xselfT);
    k_aggc<<<dim3(128, NKB), 512, 0, stream>>>(maskT, gHi, gLo, pacc, xselfT, degc,
                                               kw[l], kb[l], xoutT, v, cnt, NKB, cpk);
  }
  k_scoresk<<<16, 256, 0, stream>>>(v, xoutT, fw, fb, sT);
  k_skfinal<<<1, 64, 0, stream>>>(sT, out);
}

// Round 6
// 269.615 us; speedup vs baseline: 3.2384x; 3.2384x over previous
//
#include <hip/hip_runtime.h>
#include <hip/hip_bf16.h>
#include <cstdint>
#include <cstddef>

#define NN 4096

typedef float f32x4 __attribute__((ext_vector_type(4)));
typedef short s16x8 __attribute__((ext_vector_type(8)));

// ---------- prep: bit-plane mask maskT[chunk][d] (bit i = row sbase+i), deg counts ----------
__global__ __launch_bounds__(256) void k_prep(const float* __restrict__ K,
    unsigned* __restrict__ degc, unsigned long long* __restrict__ maskT) {
  const int lane = threadIdx.x & 63;
  const int wv = threadIdx.x >> 6;
  const int d0 = blockIdx.x * 256 + lane * 4;      // each lane owns 4 columns
  const int sbase = blockIdx.y * 256 + wv * 64;    // this wave's 64-row chunk
  const int chunk = blockIdx.y * 4 + wv;
  unsigned long long w0 = 0, w1 = 0, w2 = 0, w3 = 0;
#pragma unroll 8
  for (int i = 0; i < 64; ++i) {
    const float4 kv = *(const float4*)(K + (size_t)(sbase + i) * NN + d0);
    w0 |= ((unsigned long long)(kv.x != 0.0f)) << i;
    w1 |= ((unsigned long long)(kv.y != 0.0f)) << i;
    w2 |= ((unsigned long long)(kv.z != 0.0f)) << i;
    w3 |= ((unsigned long long)(kv.w != 0.0f)) << i;
  }
  unsigned long long* mp = maskT + (size_t)chunk * NN + d0;
  mp[0] = w0; mp[1] = w1; mp[2] = w2; mp[3] = w3;
  atomicAdd(&degc[d0 + 0], (unsigned)__popcll(w0));
  atomicAdd(&degc[d0 + 1], (unsigned)__popcll(w1));
  atomicAdd(&degc[d0 + 2], (unsigned)__popcll(w2));
  atomicAdd(&degc[d0 + 3], (unsigned)__popcll(w3));
}

// ---------- one-wave register Sinkhorn (lane = row, reg = col at entry) ----------
// 20 alternating LSE normalizations; transposes via LDS (stride-65, conflict-free).
// Ends in layout C (lane = col, reg = row) and leaves log-values in lds[r*65 + col].
__device__ __forceinline__ void lse_norm_reg(float (&m)[64]) {
  float r[32];
#pragma unroll
  for (int j = 0; j < 32; ++j) r[j] = fmaxf(m[j], m[j + 32]);
#pragma unroll
  for (int st = 16; st >= 1; st >>= 1)
#pragma unroll
    for (int j = 0; j < st; ++j) r[j] = fmaxf(r[j], r[j + st]);
  const float mx = r[0];
  float s[32];
#pragma unroll
  for (int j = 0; j < 32; ++j)
    s[j] = __expf(m[j] - mx) + __expf(m[j + 32] - mx);
#pragma unroll
  for (int st = 16; st >= 1; st >>= 1)
#pragma unroll
    for (int j = 0; j < st; ++j) s[j] += s[j + st];
  const float lse = mx + __logf(s[0]);
#pragma unroll
  for (int j = 0; j < 64; ++j) m[j] -= lse;
}

__device__ __forceinline__ void sinkhorn20(float (&m)[64], float* lds, int lane) {
  for (int it = 0; it < 19; ++it) {
    lse_norm_reg(m);
    // transpose (symmetric either direction): write rows, read columns
#pragma unroll
    for (int j = 0; j < 64; ++j) lds[lane * 65 + j] = m[j];
    asm volatile("s_waitcnt lgkmcnt(0)" ::: "memory");   // same-wave DS ordering
#pragma unroll
    for (int j = 0; j < 64; ++j) m[j] = lds[j * 65 + lane];
    asm volatile("" ::: "memory");
  }
  lse_norm_reg(m);                       // it=19, layout C (lane=col, reg=row)
#pragma unroll
  for (int j = 0; j < 64; ++j) lds[j * 65 + lane] = m[j];  // lds[row*65+col] = log val
  asm volatile("s_waitcnt lgkmcnt(0)" ::: "memory");
}

// ---------- layer-0 transform ----------
__global__ __launch_bounds__(256) void k_xform0(const float* __restrict__ K,
    const unsigned* __restrict__ degc,
    const float* __restrict__ cw, const float* __restrict__ cb,
    const float* __restrict__ sw, const float* __restrict__ sb,
    __hip_bfloat16* __restrict__ gHi, __hip_bfloat16* __restrict__ gLo,
    float* __restrict__ xselfT) {
  const int lane = threadIdx.x & 63;
  const int wv = threadIdx.x >> 6;
  const int s = blockIdx.x * 64 + lane;
  const float xv = K[(size_t)s * NN + s];          // diag(K)
  const float ds = rsqrtf((float)degc[s]);
#pragma unroll
  for (int i = 0; i < 16; ++i) {
    const int c = wv * 16 + i;
    const float gv = ds * xv * cw[c];
    const __hip_bfloat16 hi = __float2bfloat16(gv);
    gHi[(size_t)c * NN + s] = hi;
    gLo[(size_t)c * NN + s] = __float2bfloat16(gv - __bfloat162float(hi));
    xselfT[(size_t)c * NN + s] = xv * sw[c] + sb[c] + cb[c];
  }
}

// ---------- fused [sinkhorn(v) by wave0] + layer transform ----------
__global__ __launch_bounds__(256) void k_xformsk(const float* __restrict__ v,
    const float* __restrict__ xoutT, const unsigned* __restrict__ degc,
    const float* __restrict__ cw, const float* __restrict__ cb,
    const float* __restrict__ sw, const float* __restrict__ sb,
    __hip_bfloat16* __restrict__ gHi, __hip_bfloat16* __restrict__ gLo,
    float* __restrict__ xselfT) {
  __shared__ float skl[64 * 65];
  __shared__ float xt[64][64];
  const int tid = threadIdx.x;
  const int lane = tid & 63;
  const int wv = tid >> 6;
  if (wv == 0) {
    float m[64];
#pragma unroll
    for (int j = 0; j < 64; ++j) m[j] = v[lane * 64 + j] * 20.0f;  // /tau
    sinkhorn20(m, skl, lane);
  }
  __syncthreads();
  const int s = blockIdx.x * 64 + lane;
  const float skv = __expf(skl[blockIdx.x * 65 + lane]);  // sk[row=blk][col=lane]
#pragma unroll
  for (int i = 0; i < 16; ++i) {
    const int k = wv * 16 + i;
    xt[k][lane] = xoutT[(size_t)k * NN + s] + skv;  // coalesced
  }
  __syncthreads();
  float accC[16], accS[16];
#pragma unroll
  for (int i = 0; i < 16; ++i) { accC[i] = 0.f; accS[i] = 0.f; }
  for (int k = 0; k < 64; ++k) {
    const float xv = xt[k][lane];
#pragma unroll
    for (int i = 0; i < 16; ++i) {
      const int c = wv * 16 + i;
      accC[i] = fmaf(xv, cw[k * 64 + c], accC[i]);
      accS[i] = fmaf(xv, sw[k * 64 + c], accS[i]);
    }
  }
  const float ds = rsqrtf((float)degc[s]);
#pragma unroll
  for (int i = 0; i < 16; ++i) {
    const int c = wv * 16 + i;
    const float gv = ds * accC[i];
    const __hip_bfloat16 hi = __float2bfloat16(gv);
    gHi[(size_t)c * NN + s] = hi;
    gLo[(size_t)c * NN + s] = __float2bfloat16(gv - __bfloat162float(hi));
    xselfT[(size_t)c * NN + s] = accS[i] + sb[c] + cb[c];
  }
}

// ---------- MFMA masked aggregation, full K per block, in-block combine ----------
// Block handles 16 d's; 8 waves = 4 channel-tiles x 2 K-splits; no cross-block traffic.
__global__ __launch_bounds__(512) void k_agg(const unsigned long long* __restrict__ maskT,
    const __hip_bfloat16* __restrict__ gHi, const __hip_bfloat16* __restrict__ gLo,
    const float* __restrict__ xselfT, const unsigned* __restrict__ degc,
    const float* __restrict__ kw, const float* __restrict__ kb,
    float* __restrict__ xoutT, float* __restrict__ v) {
  const int tid = threadIdx.x;
  const int lane = tid & 63;
  const int wv = tid >> 6;           // 0..7
  const int mtile = wv & 3;          // channel 16-group
  const int ks = wv >> 2;            // K-split 0/1
  const int l15 = lane & 15;
  const int h = lane >> 4;           // 0..3
  const int d = blockIdx.x * 16 + l15;
  const int ch = mtile * 16 + l15;   // A-operand row (channel)
  const short* __restrict__ gh = (const short*)gHi;
  const short* __restrict__ gl = (const short*)gLo;
  f32x4 acch = {0.f, 0.f, 0.f, 0.f};
  f32x4 accl = {0.f, 0.f, 0.f, 0.f};
  const int c0 = ks * 32;
#pragma unroll 4
  for (int c = c0; c < c0 + 32; ++c) {
    const unsigned long long w = maskT[(size_t)c * NN + d];
    const unsigned half0 = (unsigned)w, half1 = (unsigned)(w >> 32);
#pragma unroll
    for (int t = 0; t < 2; ++t) {
      const unsigned half = t ? half1 : half0;
      const unsigned hb = (half >> (8 * h)) & 0xFFu;
      s16x8 bfr;
#pragma unroll
      for (int j = 0; j < 8; ++j)
        bfr[j] = (short)(((hb >> j) & 1u) * 0x3F80u);   // bit -> bf16 1.0/0.0
      const size_t abase = (size_t)ch * NN + (size_t)(c * 64 + t * 32 + 8 * h);
      const s16x8 ah = *(const s16x8*)(gh + abase);
      const s16x8 al = *(const s16x8*)(gl + abase);
      acch = __builtin_amdgcn_mfma_f32_16x16x32_bf16(ah, bfr, acch, 0, 0, 0);
      accl = __builtin_amdgcn_mfma_f32_16x16x32_bf16(al, bfr, accl, 0, 0, 0);
    }
  }
  // ---- in-block K-split reduce + combine + cls partial ----
  __shared__ float rbuf[4][64][5];   // [mtile][lane][r] (pad 5: 2-way max)
  __shared__ float vred[16][17];
  f32x4 tot;
#pragma unroll
  for (int r = 0; r < 4; ++r) tot[r] = acch[r] + accl[r];
  if (ks == 1) {
#pragma unroll
    for (int r = 0; r < 4; ++r) rbuf[mtile][lane][r] = tot[r];
  }
  __syncthreads();
  if (ks == 0) {
    // C/D layout: col = lane&15 (=d), row = (lane>>4)*4 + reg (=channel in mtile)
    const float dd = rsqrtf((float)degc[d]);
    float p = 0.f;
#pragma unroll
    for (int r = 0; r < 4; ++r) {
      const int chr = mtile * 16 + h * 4 + r;
      const float xo = xselfT[(size_t)chr * NN + d] + dd * (tot[r] + rbuf[mtile][lane][r]);
      xoutT[(size_t)chr * NN + d] = xo;
      p = fmaf(xo, kw[chr], p);
    }
    vred[l15][mtile * 4 + h] = p;
  }
  __syncthreads();
  if (tid < 16) {
    float sum = kb[0];
#pragma unroll
    for (int q = 0; q < 16; ++q) sum += vred[tid][q];
    v[blockIdx.x * 16 + tid] = sum;
  }
}

// ---------- fused [sinkhorn(v2) by wave0] + final scores -> pre-transposed sT ----------
__global__ __launch_bounds__(256) void k_scoresk(const float* __restrict__ v,
    const float* __restrict__ xoutT, const float* __restrict__ fw,
    const float* __restrict__ fb, float* __restrict__ sT) {
  __shared__ float skl[64 * 65];
  const int tid = threadIdx.x;
  const int lane = tid & 63;
  const int wv = tid >> 6;
  if (wv == 0) {
    float m[64];
#pragma unroll
    for (int j = 0; j < 64; ++j) m[j] = v[lane * 64 + j] * 20.0f;
    sinkhorn20(m, skl, lane);
  }
  __syncthreads();
  const int n = blockIdx.x * 256 + tid;
  const float skv = __expf(skl[(n >> 6) * 65 + (n & 63)]);
  float acc = 0.f, sumw = 0.f;
#pragma unroll 8
  for (int k = 0; k < 64; ++k) {
    const float w = fw[k];
    sumw += w;
    acc = fmaf(xoutT[(size_t)k * NN + n], w, acc);
  }
  sT[(n & 63) * 64 + (n >> 6)] = (acc + skv * sumw + fb[0]) * 20.0f;
}

// ---------- final Sinkhorn: one wave, sT -> out ----------
__global__ __launch_bounds__(64) void k_skfinal(const float* __restrict__ sT,
                                                float* __restrict__ out) {
  __shared__ float lds[64 * 65];
  const int lane = threadIdx.x;
  float m[64];
#pragma unroll
  for (int j = 0; j < 64; ++j) m[j] = sT[lane * 64 + j];
  sinkhorn20(m, lds, lane);
  // layout C: m[r] = log val at [r][lane]; coalesced store
#pragma unroll
  for (int r = 0; r < 64; ++r) out[r * 64 + lane] = __expf(m[r]);
}

extern "C" void kernel_launch(void* const* d_in, const int* in_sizes, int n_in,
                              void* d_out, int out_size, void* d_ws, size_t ws_size,
                              hipStream_t stream) {
  const float* K = (const float*)d_in[0];
  const float* cw[3] = {(const float*)d_in[4],  (const float*)d_in[10], (const float*)d_in[16]};
  const float* cb[3] = {(const float*)d_in[5],  (const float*)d_in[11], (const float*)d_in[17]};
  const float* sw[3] = {(const float*)d_in[6],  (const float*)d_in[12], (const float*)d_in[18]};
  const float* sb[3] = {(const float*)d_in[7],  (const float*)d_in[13], (const float*)d_in[19]};
  const float* kw[3] = {(const float*)d_in[8],  (const float*)d_in[14], (const float*)d_in[20]};
  const float* kb[3] = {(const float*)d_in[9],  (const float*)d_in[15], (const float*)d_in[21]};
  const float* fw = (const float*)d_in[22];
  const float* fb = (const float*)d_in[23];
  float* out = (float*)d_out;

  char* ws = (char*)d_ws;
  const size_t KB = 1024, MB = 1024 * 1024;
  unsigned* degc            = (unsigned*)(ws + 0);                // 16 KB
  float* v                  = (float*)(ws + 32 * KB);             // 16 KB
  float* sT                 = (float*)(ws + 48 * KB);             // 16 KB
  unsigned long long* maskT = (unsigned long long*)(ws + 64 * KB);// 2 MB
  __hip_bfloat16* gHi       = (__hip_bfloat16*)(ws + 64 * KB + 2 * MB);            // 512 KB
  __hip_bfloat16* gLo       = (__hip_bfloat16*)(ws + 64 * KB + 2 * MB + 512 * KB); // 512 KB
  float* xselfT             = (float*)(ws + 64 * KB + 3 * MB);    // 1 MB
  float* xoutT              = (float*)(ws + 64 * KB + 4 * MB);    // 1 MB
  (void)in_sizes; (void)n_in; (void)out_size; (void)ws_size;

  hipMemsetAsync(degc, 0, NN * sizeof(unsigned), stream);
  k_prep<<<dim3(16, 16), 256, 0, stream>>>(K, degc, maskT);

  k_xform0<<<64, 256, 0, stream>>>(K, degc, cw[0], cb[0], sw[0], sb[0], gHi, gLo, xselfT);
  k_agg<<<256, 512, 0, stream>>>(maskT, gHi, gLo, xselfT, degc, kw[0], kb[0], xoutT, v);
  for (int l = 1; l < 3; ++l) {
    k_xformsk<<<64, 256, 0, stream>>>(v, xoutT, degc, cw[l], cb[l], sw[l], sb[l],
                                      gHi, gLo, xselfT);
    k_agg<<<256, 512, 0, stream>>>(maskT, gHi, gLo, xselfT, degc, kw[l], kb[l], xoutT, v);
  }
  k_scoresk<<<16, 256, 0, stream>>>(v, xoutT, fw, fb, sT);
  k_skfinal<<<1, 64, 0, stream>>>(sT, out);
}

// Round 7
// 230.793 us; speedup vs baseline: 3.7831x; 1.1682x over previous
//
#include <hip/hip_runtime.h>
#include <hip/hip_bf16.h>
#include <cstdint>
#include <cstddef>

#define NN 4096

typedef float f32x4 __attribute__((ext_vector_type(4)));
typedef short s16x8 __attribute__((ext_vector_type(8)));

// ---------- prep: bit-plane mask maskT[chunk][d] (bit i = row sbase+i), deg counts ----------
__global__ __launch_bounds__(256) void k_prep(const float* __restrict__ K,
    unsigned* __restrict__ degc, unsigned long long* __restrict__ maskT) {
  const int lane = threadIdx.x & 63;
  const int wv = threadIdx.x >> 6;
  const int d0 = blockIdx.x * 256 + lane * 4;      // each lane owns 4 columns
  const int sbase = blockIdx.y * 256 + wv * 64;    // this wave's 64-row chunk
  const int chunk = blockIdx.y * 4 + wv;
  unsigned long long w0 = 0, w1 = 0, w2 = 0, w3 = 0;
#pragma unroll 8
  for (int i = 0; i < 64; ++i) {
    const float4 kv = *(const float4*)(K + (size_t)(sbase + i) * NN + d0);
    w0 |= ((unsigned long long)(kv.x != 0.0f)) << i;
    w1 |= ((unsigned long long)(kv.y != 0.0f)) << i;
    w2 |= ((unsigned long long)(kv.z != 0.0f)) << i;
    w3 |= ((unsigned long long)(kv.w != 0.0f)) << i;
  }
  unsigned long long* mp = maskT + (size_t)chunk * NN + d0;
  mp[0] = w0; mp[1] = w1; mp[2] = w2; mp[3] = w3;
  atomicAdd(&degc[d0 + 0], (unsigned)__popcll(w0));
  atomicAdd(&degc[d0 + 1], (unsigned)__popcll(w1));
  atomicAdd(&degc[d0 + 2], (unsigned)__popcll(w2));
  atomicAdd(&degc[d0 + 3], (unsigned)__popcll(w3));
}

// ---------- block-parallel (256-thread) LDS Sinkhorn, 20 alternating LSE norms ----------
// thread t owns 16 elements of row/col g = t>>2 (quad lane q = t&3 owns cols q*16..+15).
// Quad all-reduce via ds_swizzle XOR butterflies; LDS [64][65] -> <=2-way aliasing (free).
__device__ __forceinline__ float swz_xor1(float x) {
  return __int_as_float(__builtin_amdgcn_ds_swizzle(__float_as_int(x), 0x041F));
}
__device__ __forceinline__ float swz_xor2(float x) {
  return __int_as_float(__builtin_amdgcn_ds_swizzle(__float_as_int(x), 0x081F));
}

__device__ __forceinline__ void sinkhorn_block(float (*m)[65], int tid) {
  const int g = tid >> 2;
  const int q = tid & 3;
  for (int it = 0; it < 20; ++it) {
    float x[16];
    if ((it & 1) == 0) {
#pragma unroll
      for (int j = 0; j < 16; ++j) x[j] = m[g][q * 16 + j];
    } else {
#pragma unroll
      for (int j = 0; j < 16; ++j) x[j] = m[q * 16 + j][g];
    }
    float mx = x[0];
#pragma unroll
    for (int j = 1; j < 16; ++j) mx = fmaxf(mx, x[j]);
    mx = fmaxf(mx, swz_xor1(mx));
    mx = fmaxf(mx, swz_xor2(mx));
    float sm = 0.f;
#pragma unroll
    for (int j = 0; j < 16; ++j) sm += __expf(x[j] - mx);
    sm += swz_xor1(sm);
    sm += swz_xor2(sm);
    const float lse = mx + __logf(sm);
    if ((it & 1) == 0) {
#pragma unroll
      for (int j = 0; j < 16; ++j) m[g][q * 16 + j] = x[j] - lse;
    } else {
#pragma unroll
      for (int j = 0; j < 16; ++j) m[q * 16 + j][g] = x[j] - lse;
    }
    __syncthreads();
  }
}

// ---------- layer-0 transform ----------
__global__ __launch_bounds__(256) void k_xform0(const float* __restrict__ K,
    const unsigned* __restrict__ degc,
    const float* __restrict__ cw, const float* __restrict__ cb,
    const float* __restrict__ sw, const float* __restrict__ sb,
    __hip_bfloat16* __restrict__ gHi, __hip_bfloat16* __restrict__ gLo,
    float* __restrict__ xselfT) {
  const int lane = threadIdx.x & 63;
  const int wv = threadIdx.x >> 6;
  const int s = blockIdx.x * 64 + lane;
  const float xv = K[(size_t)s * NN + s];          // diag(K)
  const float ds = rsqrtf((float)degc[s]);
#pragma unroll
  for (int i = 0; i < 16; ++i) {
    const int c = wv * 16 + i;
    const float gv = ds * xv * cw[c];
    const __hip_bfloat16 hi = __float2bfloat16(gv);
    gHi[(size_t)c * NN + s] = hi;
    gLo[(size_t)c * NN + s] = __float2bfloat16(gv - __bfloat162float(hi));
    xselfT[(size_t)c * NN + s] = xv * sw[c] + sb[c] + cb[c];
  }
}

// ---------- fused [block-parallel sinkhorn(v)] + layer transform ----------
__global__ __launch_bounds__(256) void k_xformsk(const float* __restrict__ v,
    const float* __restrict__ xoutT, const unsigned* __restrict__ degc,
    const float* __restrict__ cw, const float* __restrict__ cb,
    const float* __restrict__ sw, const float* __restrict__ sb,
    __hip_bfloat16* __restrict__ gHi, __hip_bfloat16* __restrict__ gLo,
    float* __restrict__ xselfT) {
  __shared__ float skl[64][65];
  __shared__ float xt[64][64];
  const int tid = threadIdx.x;
  const int lane = tid & 63;
  const int wv = tid >> 6;
#pragma unroll
  for (int j = 0; j < 16; ++j) {
    const int e = j * 256 + tid;
    skl[e >> 6][e & 63] = v[e] * 20.0f;            // /tau
  }
  __syncthreads();
  sinkhorn_block(skl, tid);
  const int s = blockIdx.x * 64 + lane;
  const float skv = __expf(skl[blockIdx.x][lane]); // sk[row=blk][col=lane]
#pragma unroll
  for (int i = 0; i < 16; ++i) {
    const int k = wv * 16 + i;
    xt[k][lane] = xoutT[(size_t)k * NN + s] + skv; // coalesced
  }
  __syncthreads();
  float accC[16], accS[16];
#pragma unroll
  for (int i = 0; i < 16; ++i) { accC[i] = 0.f; accS[i] = 0.f; }
  for (int k = 0; k < 64; ++k) {
    const float xv = xt[k][lane];
#pragma unroll
    for (int i = 0; i < 16; ++i) {
      const int c = wv * 16 + i;
      accC[i] = fmaf(xv, cw[k * 64 + c], accC[i]);
      accS[i] = fmaf(xv, sw[k * 64 + c], accS[i]);
    }
  }
  const float ds = rsqrtf((float)degc[s]);
#pragma unroll
  for (int i = 0; i < 16; ++i) {
    const int c = wv * 16 + i;
    const float gv = ds * accC[i];
    const __hip_bfloat16 hi = __float2bfloat16(gv);
    gHi[(size_t)c * NN + s] = hi;
    gLo[(size_t)c * NN + s] = __float2bfloat16(gv - __bfloat162float(hi));
    xselfT[(size_t)c * NN + s] = accS[i] + sb[c] + cb[c];
  }
}

// ---------- MFMA masked aggregation, full K per block, in-block combine ----------
// Block handles 16 d's; 8 waves = 4 channel-tiles x 2 K-splits; no cross-block traffic.
__global__ __launch_bounds__(512) void k_agg(const unsigned long long* __restrict__ maskT,
    const __hip_bfloat16* __restrict__ gHi, const __hip_bfloat16* __restrict__ gLo,
    const float* __restrict__ xselfT, const unsigned* __restrict__ degc,
    const float* __restrict__ kw, const float* __restrict__ kb,
    float* __restrict__ xoutT, float* __restrict__ v) {
  const int tid = threadIdx.x;
  const int lane = tid & 63;
  const int wv = tid >> 6;           // 0..7
  const int mtile = wv & 3;          // channel 16-group
  const int ks = wv >> 2;            // K-split 0/1
  const int l15 = lane & 15;
  const int h = lane >> 4;           // 0..3
  const int d = blockIdx.x * 16 + l15;
  const int ch = mtile * 16 + l15;   // A-operand row (channel)
  const short* __restrict__ gh = (const short*)gHi;
  const short* __restrict__ gl = (const short*)gLo;
  f32x4 acch = {0.f, 0.f, 0.f, 0.f};
  f32x4 accl = {0.f, 0.f, 0.f, 0.f};
  const int c0 = ks * 32;
#pragma unroll 4
  for (int c = c0; c < c0 + 32; ++c) {
    const unsigned long long w = maskT[(size_t)c * NN + d];
    const unsigned half0 = (unsigned)w, half1 = (unsigned)(w >> 32);
#pragma unroll
    for (int t = 0; t < 2; ++t) {
      const unsigned half = t ? half1 : half0;
      const unsigned hb = (half >> (8 * h)) & 0xFFu;
      s16x8 bfr;
#pragma unroll
      for (int j = 0; j < 8; ++j)
        bfr[j] = (short)(((hb >> j) & 1u) * 0x3F80u);   // bit -> bf16 1.0/0.0
      const size_t abase = (size_t)ch * NN + (size_t)(c * 64 + t * 32 + 8 * h);
      const s16x8 ah = *(const s16x8*)(gh + abase);
      const s16x8 al = *(const s16x8*)(gl + abase);
      acch = __builtin_amdgcn_mfma_f32_16x16x32_bf16(ah, bfr, acch, 0, 0, 0);
      accl = __builtin_amdgcn_mfma_f32_16x16x32_bf16(al, bfr, accl, 0, 0, 0);
    }
  }
  // ---- in-block K-split reduce + combine + cls partial ----
  __shared__ float rbuf[4][64][5];   // [mtile][lane][r] (pad 5: 2-way max)
  __shared__ float vred[16][17];
  f32x4 tot;
#pragma unroll
  for (int r = 0; r < 4; ++r) tot[r] = acch[r] + accl[r];
  if (ks == 1) {
#pragma unroll
    for (int r = 0; r < 4; ++r) rbuf[mtile][lane][r] = tot[r];
  }
  __syncthreads();
  if (ks == 0) {
    // C/D layout: col = lane&15 (=d), row = (lane>>4)*4 + reg (=channel in mtile)
    const float dd = rsqrtf((float)degc[d]);
    float p = 0.f;
#pragma unroll
    for (int r = 0; r < 4; ++r) {
      const int chr = mtile * 16 + h * 4 + r;
      const float xo = xselfT[(size_t)chr * NN + d] + dd * (tot[r] + rbuf[mtile][lane][r]);
      xoutT[(size_t)chr * NN + d] = xo;
      p = fmaf(xo, kw[chr], p);
    }
    vred[l15][mtile * 4 + h] = p;
  }
  __syncthreads();
  if (tid < 16) {
    float sum = kb[0];
#pragma unroll
    for (int q = 0; q < 16; ++q) sum += vred[tid][q];
    v[blockIdx.x * 16 + tid] = sum;
  }
}

// ---------- fused [block-parallel sinkhorn(v2)] + final scores -> pre-transposed sT ----------
__global__ __launch_bounds__(256) void k_scoresk(const float* __restrict__ v,
    const float* __restrict__ xoutT, const float* __restrict__ fw,
    const float* __restrict__ fb, float* __restrict__ sT) {
  __shared__ float skl[64][65];
  const int tid = threadIdx.x;
#pragma unroll
  for (int j = 0; j < 16; ++j) {
    const int e = j * 256 + tid;
    skl[e >> 6][e & 63] = v[e] * 20.0f;
  }
  __syncthreads();
  sinkhorn_block(skl, tid);
  const int n = blockIdx.x * 256 + tid;
  const float skv = __expf(skl[n >> 6][n & 63]);
  float acc = 0.f, sumw = 0.f;
#pragma unroll 8
  for (int k = 0; k < 64; ++k) {
    const float w = fw[k];
    sumw += w;
    acc = fmaf(xoutT[(size_t)k * NN + n], w, acc);
  }
  sT[(n & 63) * 64 + (n >> 6)] = (acc + skv * sumw + fb[0]) * 20.0f;
}

// ---------- final Sinkhorn: one 256-thread block, sT -> out ----------
__global__ __launch_bounds__(256) void k_skfinal(const float* __restrict__ sT,
                                                 float* __restrict__ out) {
  __shared__ float m[64][65];
  const int tid = threadIdx.x;
#pragma unroll
  for (int j = 0; j < 16; ++j) {
    const int e = j * 256 + tid;
    m[e >> 6][e & 63] = sT[e];
  }
  __syncthreads();
  sinkhorn_block(m, tid);
#pragma unroll
  for (int j = 0; j < 16; ++j) {
    const int e = j * 256 + tid;
    out[e] = __expf(m[e >> 6][e & 63]);
  }
}

extern "C" void kernel_launch(void* const* d_in, const int* in_sizes, int n_in,
                              void* d_out, int out_size, void* d_ws, size_t ws_size,
                              hipStream_t stream) {
  const float* K = (const float*)d_in[0];
  const float* cw[3] = {(const float*)d_in[4],  (const float*)d_in[10], (const float*)d_in[16]};
  const float* cb[3] = {(const float*)d_in[5],  (const float*)d_in[11], (const float*)d_in[17]};
  const float* sw[3] = {(const float*)d_in[6],  (const float*)d_in[12], (const float*)d_in[18]};
  const float* sb[3] = {(const float*)d_in[7],  (const float*)d_in[13], (const float*)d_in[19]};
  const float* kw[3] = {(const float*)d_in[8],  (const float*)d_in[14], (const float*)d_in[20]};
  const float* kb[3] = {(const float*)d_in[9],  (const float*)d_in[15], (const float*)d_in[21]};
  const float* fw = (const float*)d_in[22];
  const float* fb = (const float*)d_in[23];
  float* out = (float*)d_out;

  char* ws = (char*)d_ws;
  const size_t KB = 1024, MB = 1024 * 1024;
  unsigned* degc            = (unsigned*)(ws + 0);                // 16 KB
  float* v                  = (float*)(ws + 32 * KB);             // 16 KB
  float* sT                 = (float*)(ws + 48 * KB);             // 16 KB
  unsigned long long* maskT = (unsigned long long*)(ws + 64 * KB);// 2 MB
  __hip_bfloat16* gHi       = (__hip_bfloat16*)(ws + 64 * KB + 2 * MB);            // 512 KB
  __hip_bfloat16* gLo       = (__hip_bfloat16*)(ws + 64 * KB + 2 * MB + 512 * KB); // 512 KB
  float* xselfT             = (float*)(ws + 64 * KB + 3 * MB);    // 1 MB
  float* xoutT              = (float*)(ws + 64 * KB + 4 * MB);    // 1 MB
  (void)in_sizes; (void)n_in; (void)out_size; (void)ws_size;

  hipMemsetAsync(degc, 0, NN * sizeof(unsigned), stream);
  k_prep<<<dim3(16, 16), 256, 0, stream>>>(K, degc, maskT);

  k_xform0<<<64, 256, 0, stream>>>(K, degc, cw[0], cb[0], sw[0], sb[0], gHi, gLo, xselfT);
  k_agg<<<256, 512, 0, stream>>>(maskT, gHi, gLo, xselfT, degc, kw[0], kb[0], xoutT, v);
  for (int l = 1; l < 3; ++l) {
    k_xformsk<<<64, 256, 0, stream>>>(v, xoutT, degc, cw[l], cb[l], sw[l], sb[l],
                                      gHi, gLo, xselfT);
    k_agg<<<256, 512, 0, stream>>>(maskT, gHi, gLo, xselfT, degc, kw[l], kb[l], xoutT, v);
  }
  k_scoresk<<<16, 256, 0, stream>>>(v, xoutT, fw, fb, sT);
  k_skfinal<<<1, 256, 0, stream>>>(sT, out);
}